// Round 16
// baseline (321.044 us; speedup 1.0000x reference)
//
#include <hip/hip_runtime.h>

// ---------------------------------------------------------------------------
// Swin-style windowed MHA block, MI355X/gfx950.
// R16 = R14 resubmitted a 2nd time (two container deaths in a row; kernel
// has never run on HW).
// R14: fixes R13's xpose under-staging bug (q<4 -> q<8: half of tb was
// uninitialized LDS => NaN). Drops the 50MB aow buffer (ws back to the
// proven 50.9MB) by merging attn_core+proj into ONE kernel with a single
// __syncthreads: 768 thr = 2 windows x 6 heads; AO kept in LDS; proj reads
// cross-head AO from LDS; y = x + proj RMW'd in place over xw.
//   prep  : weights->bf16 + biasx gather.
//   xpose : x (BCHW f32) -> xw[2048][64][192] bf16.
//   attn  : QKV (A-frags straight from xw) -> scores -> softmax -> PV -> AO
//           (LDS) -> [1 barrier] -> proj -> y in place over xw.
//   mlp   : R8-proven kernel, reads y (=xw), writes out fp32.
// ---------------------------------------------------------------------------

typedef short          s16x8 __attribute__((ext_vector_type(8)));
typedef unsigned short u16x4 __attribute__((ext_vector_type(4)));
typedef unsigned short u16x8 __attribute__((ext_vector_type(8)));
typedef float          f32x4 __attribute__((ext_vector_type(4)));

#define MFMA(A, B, C) __builtin_amdgcn_mfma_f32_16x16x32_bf16((A), (B), (C), 0, 0, 0)

__device__ __forceinline__ unsigned short f2b(float f) {
  unsigned x = __float_as_uint(f);
  x = (x + 0x7FFFu + ((x >> 16) & 1u)) >> 16;   // RNE
  return (unsigned short)x;
}
__device__ __forceinline__ float b2f(unsigned short u) {
  return __uint_as_float(((unsigned)u) << 16);
}
__device__ __forceinline__ u16x4 pk4(f32x4 v) {
  u16x4 r;
  r[0] = f2b(v[0]); r[1] = f2b(v[1]); r[2] = f2b(v[2]); r[3] = f2b(v[3]);
  return r;
}

// [64][32] tiles (Q,K,P-half,AO): 16B-chunk XOR keyed on (t>>1)&3
__device__ __forceinline__ int swz32(int t, int c) {
  return t * 32 + ((((c >> 3) ^ (t >> 1)) & 3) << 3) + (c & 7);
}
// Vt [32][64]: chunk XOR keyed on (d + (d>>3)) & 7
__device__ __forceinline__ int swzV(int d, int t) {
  return d * 64 + ((((t >> 3) ^ (d + (d >> 3))) & 7) << 3) + (t & 7);
}

#define XSTR   200
#define QSCALE 0.17677669529663687f

// workspace offsets
#define WOFF_QKV   0            // u16 elems
#define WOFF_PROJ  110592
#define WOFF_MLP1  147456
#define WOFF_MLP2  221184
#define WOFF_BIASX_BYTES 516096               // float[4096] -> ends 532480
#define WOFF_XW_BYTES    532480               // u16[2048*64*192] = 50331648 B (xw, then y in place)

// ---------------------------------------------------------------------------
__global__ void prep_kernel(const float* __restrict__ qkv_w,
                            const float* __restrict__ proj_w,
                            const float* __restrict__ mlp1_w,
                            const float* __restrict__ mlp2_w,
                            const float* __restrict__ bias_table,
                            const int*   __restrict__ rel_index,
                            unsigned short* __restrict__ qkv_wb,
                            unsigned short* __restrict__ proj_wb,
                            unsigned short* __restrict__ mlp1_wb,
                            unsigned short* __restrict__ mlp2_wb,
                            float* __restrict__ biasx) {
  int j = blockIdx.x * 256 + threadIdx.x;   // 262144 jobs
  if (j < 110592) {
    float v = qkv_w[j];
    if (j < 36864) v *= QSCALE;
    qkv_wb[j] = f2b(v);
  } else if (j < 147456) {
    proj_wb[j - 110592] = f2b(proj_w[j - 110592]);
  } else if (j < 221184) {
    mlp1_wb[j - 147456] = f2b(mlp1_w[j - 147456]);
  } else if (j < 258048) {
    mlp2_wb[j - 221184] = f2b(mlp2_w[j - 221184]);
  } else {
    int e = j - 258048;                     // 0..4095
    int l = e >> 6, v = e & 63;
    int tm = v >> 4, tn = (v >> 2) & 3, r = v & 3;
    int q = tn * 16 + (l & 15);
    int k = tm * 16 + (l >> 4) * 4 + r;
    biasx[e] = bias_table[rel_index[q * 64 + k]];
  }
}

// ---------------------------------------------------------------------------
// x [B=8][C=192][H=128][W=128] f32  ->  xw [2048][64][192] bf16
// block = one (b, h) row-strip; stages [192 c][128 w] in LDS, writes 16 windows.
#define TSTR 129
__global__ __launch_bounds__(256) void xpose_kernel(
    const float* __restrict__ x, unsigned short* __restrict__ xw) {
  __shared__ unsigned short tb[192 * TSTR];  // 49536 B
  const int tid = threadIdx.x;
  const int s   = ((blockIdx.x & 7) << 7) | (blockIdx.x >> 3);  // XCD swizzle, 1024=8*128
  const int b   = s >> 7;
  const int hr  = s & 127;
  const float* xrow = x + (size_t)b * 192 * 16384 + (size_t)hr * 128;

  // stage: 192 c x 4 wseg (32 floats each) = 768 jobs; q<8 covers ALL 32
#pragma unroll
  for (int it = 0; it < 3; ++it) {
    int job = tid + 256 * it;
    int c = job >> 2, wseg = job & 3;
    const float* src = xrow + (size_t)c * 16384 + wseg * 32;
    unsigned short* dst = &tb[c * TSTR + wseg * 32];
#pragma unroll
    for (int q = 0; q < 8; ++q) {
      f32x4 v = *(const f32x4*)(src + q * 4);
      u16x4 p; p[0] = f2b(v[0]); p[1] = f2b(v[1]); p[2] = f2b(v[2]); p[3] = f2b(v[3]);
      *(u16x4*)&dst[q * 4] = p;
    }
  }
  __syncthreads();

  // write: 16 wwi x 8 w' x 24 cseg = 3072 jobs, 16B contiguous runs
  const int winb = b * 256 + (hr >> 3) * 16;
  const int i = hr & 7;
#pragma unroll
  for (int it = 0; it < 12; ++it) {
    int job = tid + 256 * it;
    int wwi = job / 192;
    int rem = job - wwi * 192;
    int t7 = rem / 24;
    int cseg = rem - t7 * 24;
    u16x8 v;
#pragma unroll
    for (int jj = 0; jj < 8; ++jj)
      v[jj] = tb[(cseg * 8 + jj) * TSTR + wwi * 8 + t7];
    unsigned short* dst = xw + (size_t)(winb + wwi) * 12288 + (i * 8 + t7) * 192 + cseg * 8;
    *(u16x8*)dst = v;
  }
}

// ---------------------------------------------------------------------------
// 768 thr = 2 windows x 6 heads. ONE __syncthreads (AO visibility).
__global__ __launch_bounds__(768, 3) void attn_kernel(
    const unsigned short* __restrict__ xw,   // in: xw; out: y in place
    const unsigned short* __restrict__ qkv_wb, const float* __restrict__ qkv_b,
    const unsigned short* __restrict__ proj_wb, const float* __restrict__ proj_b,
    const float* __restrict__ biasx) {
  __shared__ __align__(16) unsigned short sm[2 * 6 * 4096];  // 98304 B

  const int tid  = threadIdx.x;
  const int lane = tid & 63;
  const int wv   = tid >> 6;          // 0..11
  const int wid  = (wv >= 6) ? 1 : 0;
  const int hd   = wv - wid * 6;
  const int l15  = lane & 15;
  const int lg   = lane >> 4;
  const int pair = ((blockIdx.x & 7) << 7) | (blockIdx.x >> 3);  // XCD swizzle
  const int win  = pair * 2 + wid;
  const int oQ   = hd * 32;

  unsigned short* xww = (unsigned short*)xw + (size_t)win * 12288;
  unsigned short* hb  = sm + (wid * 6 + hd) * 4096;
  unsigned short* R0  = hb;            // Q -> Phalf -> AO (4KB, [64][32] swz32)
  unsigned short* R1  = hb + 2048;     // K -> Vt          (4KB)

  // ---------------- QKV: Q^T,K^T = mfma(w, x);  V = mfma(x, w) ----------------
  f32x4 accqT[2][4], acckT[2][4], accv[4][2];
#pragma unroll
  for (int m = 0; m < 2; ++m) {
    f32x4 bq4 = *(const f32x4*)&qkv_b[oQ + m * 16 + lg * 4];
    f32x4 bk4 = *(const f32x4*)&qkv_b[192 + oQ + m * 16 + lg * 4];
#pragma unroll
    for (int tn = 0; tn < 4; ++tn) {
      accqT[m][tn] = bq4 * QSCALE;
      acckT[m][tn] = bk4;
    }
  }
#pragma unroll
  for (int nt = 0; nt < 2; ++nt) {
    const float bv = qkv_b[384 + oQ + nt * 16 + l15];
#pragma unroll
    for (int mt = 0; mt < 4; ++mt) accv[mt][nt] = (f32x4){bv, bv, bv, bv};
  }
#pragma unroll
  for (int ks = 0; ks < 6; ++ks) {
    const int k0 = ks * 32 + lg * 8;
    s16x8 bf[4];
#pragma unroll
    for (int tn = 0; tn < 4; ++tn)
      bf[tn] = *(const s16x8*)&xww[(tn * 16 + l15) * 192 + k0];
    s16x8 wq[2], wk[2], wvv[2];
#pragma unroll
    for (int m = 0; m < 2; ++m) {
      wq[m]  = *(const s16x8*)&qkv_wb[(size_t)(oQ + m * 16 + l15) * 192 + k0];
      wk[m]  = *(const s16x8*)&qkv_wb[(size_t)(192 + oQ + m * 16 + l15) * 192 + k0];
      wvv[m] = *(const s16x8*)&qkv_wb[(size_t)(384 + oQ + m * 16 + l15) * 192 + k0];
    }
#pragma unroll
    for (int m = 0; m < 2; ++m)
#pragma unroll
      for (int tn = 0; tn < 4; ++tn) {
        accqT[m][tn] = MFMA(wq[m], bf[tn], accqT[m][tn]);
        acckT[m][tn] = MFMA(wk[m], bf[tn], acckT[m][tn]);
      }
#pragma unroll
    for (int mt = 0; mt < 4; ++mt)
#pragma unroll
      for (int nt = 0; nt < 2; ++nt)
        accv[mt][nt] = MFMA(bf[mt], wvv[nt], accv[mt][nt]);
  }
  // Q,K stores: C[d][t] regs run along d -> u16x4 into row-major [t][d]
#pragma unroll
  for (int m = 0; m < 2; ++m)
#pragma unroll
    for (int tn = 0; tn < 4; ++tn) {
      const int t = tn * 16 + l15, d0 = m * 16 + lg * 4;
      *(u16x4*)&R0[swz32(t, d0)] = pk4(accqT[m][tn]);
      *(u16x4*)&R1[swz32(t, d0)] = pk4(acckT[m][tn]);
    }
  u16x4 vreg[4][2];
#pragma unroll
  for (int mt = 0; mt < 4; ++mt)
#pragma unroll
    for (int nt = 0; nt < 2; ++nt)
      vreg[mt][nt] = pk4(accv[mt][nt]);

  // ---------------- scores^T = mfma(K, Q) + bias ----------------
  const float* bxp = biasx + lane * 64;
  s16x8 kf[4], qf[4];
#pragma unroll
  for (int tm = 0; tm < 4; ++tm)
    kf[tm] = *(const s16x8*)&R1[swz32(tm * 16 + l15, lg * 8)];
#pragma unroll
  for (int tn = 0; tn < 4; ++tn)
    qf[tn] = *(const s16x8*)&R0[swz32(tn * 16 + l15, lg * 8)];
  // Vt over K (in-wave DS order: writes cannot pass the kf reads)
#pragma unroll
  for (int mt = 0; mt < 4; ++mt)
#pragma unroll
    for (int nt = 0; nt < 2; ++nt)
      *(u16x4*)&R1[swzV(nt * 16 + l15, mt * 16 + lg * 4)] = vreg[mt][nt];

  f32x4 sc[4][4];
#pragma unroll
  for (int tm = 0; tm < 4; ++tm)
#pragma unroll
    for (int tn = 0; tn < 4; ++tn) {
      f32x4 bfr = *(const f32x4*)&bxp[tm * 16 + tn * 4];
      sc[tm][tn] = MFMA(kf[tm], qf[tn], bfr);
    }
  // softmax over keys
#pragma unroll
  for (int tn = 0; tn < 4; ++tn) {
    float mx = sc[0][tn][0];
#pragma unroll
    for (int tm = 0; tm < 4; ++tm)
#pragma unroll
      for (int r = 0; r < 4; ++r) mx = fmaxf(mx, sc[tm][tn][r]);
    mx = fmaxf(mx, __shfl_xor(mx, 16));
    mx = fmaxf(mx, __shfl_xor(mx, 32));
    float sum = 0.f;
#pragma unroll
    for (int tm = 0; tm < 4; ++tm)
#pragma unroll
      for (int r = 0; r < 4; ++r) {
        float e = __expf(sc[tm][tn][r] - mx);
        sc[tm][tn][r] = e;
        sum += e;
      }
    sum += __shfl_xor(sum, 16);
    sum += __shfl_xor(sum, 32);
    const float inv = 1.0f / sum;
#pragma unroll
    for (int tm = 0; tm < 4; ++tm)
#pragma unroll
      for (int r = 0; r < 4; ++r) sc[tm][tn][r] *= inv;
  }

  // ---------------- PV as out^T = mfma(Vt, P), P in halves over R0 ----------------
  f32x4 oT[2][4];
#pragma unroll
  for (int m = 0; m < 2; ++m)
#pragma unroll
    for (int tn = 0; tn < 4; ++tn) oT[m][tn] = (f32x4){0.f, 0.f, 0.f, 0.f};
#pragma unroll
  for (int half = 0; half < 2; ++half) {
#pragma unroll
    for (int tm = 0; tm < 2; ++tm)
#pragma unroll
      for (int tn = 0; tn < 4; ++tn)
        *(u16x4*)&R0[swz32(tn * 16 + l15, tm * 16 + lg * 4)] =
            pk4(sc[half * 2 + tm][tn]);
    s16x8 bp[4], av[2];
#pragma unroll
    for (int tn = 0; tn < 4; ++tn)
      bp[tn] = *(const s16x8*)&R0[swz32(tn * 16 + l15, lg * 8)];
#pragma unroll
    for (int m = 0; m < 2; ++m)
      av[m] = *(const s16x8*)&R1[swzV(m * 16 + l15, half * 32 + lg * 8)];
#pragma unroll
    for (int m = 0; m < 2; ++m)
#pragma unroll
      for (int tn = 0; tn < 4; ++tn)
        oT[m][tn] = MFMA(av[m], bp[tn], oT[m][tn]);
  }
  // AO store into R0 (LDS): C[d][t] -> u16x4 into [t][d]
#pragma unroll
  for (int m = 0; m < 2; ++m)
#pragma unroll
    for (int tn = 0; tn < 4; ++tn)
      *(u16x4*)&R0[swz32(tn * 16 + l15, m * 16 + lg * 4)] = pk4(oT[m][tn]);
  __syncthreads();  // the ONLY barrier: all heads' AO visible

  // ---------------- proj^T = mfma(Wp, AO) + residual RMW over xw ----------------
  f32x4 pjT[2][4];
#pragma unroll
  for (int m = 0; m < 2; ++m) {
    f32x4 bp4 = *(const f32x4*)&proj_b[oQ + m * 16 + lg * 4];
#pragma unroll
    for (int tn = 0; tn < 4; ++tn) pjT[m][tn] = bp4;
  }
#pragma unroll
  for (int hh = 0; hh < 6; ++hh) {
    const unsigned short* aoh = sm + (wid * 6 + hh) * 4096;   // head hh's AO (R0)
    s16x8 aa[4];
#pragma unroll
    for (int tn = 0; tn < 4; ++tn)
      aa[tn] = *(const s16x8*)&aoh[swz32(tn * 16 + l15, lg * 8)];
    s16x8 wp[2];
#pragma unroll
    for (int m = 0; m < 2; ++m)
      wp[m] = *(const s16x8*)&proj_wb[(size_t)(oQ + m * 16 + l15) * 192 + hh * 32 + lg * 8];
#pragma unroll
    for (int m = 0; m < 2; ++m)
#pragma unroll
      for (int tn = 0; tn < 4; ++tn)
        pjT[m][tn] = MFMA(wp[m], aa[tn], pjT[m][tn]);
  }
  // y = x + proj, in place over xw (wave-private cols, lane-private cells)
#pragma unroll
  for (int m = 0; m < 2; ++m)
#pragma unroll
    for (int tn = 0; tn < 4; ++tn) {
      const int t = tn * 16 + l15, o0 = oQ + m * 16 + lg * 4;
      u16x4 old = *(const u16x4*)&xww[t * 192 + o0];
      f32x4 s;
#pragma unroll
      for (int r = 0; r < 4; ++r) s[r] = pjT[m][tn][r] + b2f(old[r]);
      *(u16x4*)&xww[t * 192 + o0] = pk4(s);
    }
}

// ---------------------------------------------------------------------------
__global__ __launch_bounds__(256, 4) void mlp_kernel(
    const unsigned short* __restrict__ y_win,
    const unsigned short* __restrict__ w1b, const float* __restrict__ b1,
    const unsigned short* __restrict__ w2b, const float* __restrict__ b2,
    float* __restrict__ out) {
  __shared__ __align__(16) unsigned short sm2[2 * 64 * XSTR];
  unsigned short* yb = sm2;
  unsigned short* wk = sm2 + 64 * XSTR;

  const int tid  = threadIdx.x;
  const int lane = tid & 63;
  const int wv   = tid >> 6;
  const int l15  = lane & 15;
  const int lg   = lane >> 4;
  const int win  = ((blockIdx.x & 7) << 8) | (blockIdx.x >> 3);
  const int bb   = win >> 8;
  const int wh   = (win >> 4) & 15;
  const int wwi  = win & 15;

  const unsigned short* ywp = y_win + (size_t)win * 12288;
#pragma unroll
  for (int it = 0; it < 6; ++it) {
    int job = tid + 256 * it;
    int t = job / 24;
    int seg = job - t * 24;
    *(u16x8*)&yb[t * XSTR + seg * 8] = *(const u16x8*)&ywp[(size_t)job * 8];
  }
  __syncthreads();

#pragma unroll
  for (int i = 0; i < 3; ++i) {
    const int na = (3 * wv + i) * 16 + l15;
    const int nb = na + 192;
    f32x4 aacc[4], bacc[4];
    const float ba = b1[na], bbv = b1[nb];
#pragma unroll
    for (int m = 0; m < 4; ++m) {
      aacc[m] = (f32x4){ba, ba, ba, ba};
      bacc[m] = (f32x4){bbv, bbv, bbv, bbv};
    }
#pragma unroll
    for (int ks = 0; ks < 6; ++ks) {
      const int k0 = ks * 32 + lg * 8;
      s16x8 af[4];
#pragma unroll
      for (int m = 0; m < 4; ++m)
        af[m] = *(const s16x8*)&yb[(m * 16 + l15) * XSTR + k0];
      s16x8 wa = *(const s16x8*)&w1b[(size_t)na * 192 + k0];
      s16x8 wb = *(const s16x8*)&w1b[(size_t)nb * 192 + k0];
#pragma unroll
      for (int m = 0; m < 4; ++m) {
        aacc[m] = MFMA(af[m], wa, aacc[m]);
        bacc[m] = MFMA(af[m], wb, bacc[m]);
      }
    }
#pragma unroll
    for (int m = 0; m < 4; ++m)
#pragma unroll
      for (int r = 0; r < 4; ++r) {
        const float g = aacc[m][r] * (1.0f / (1.0f + __expf(-bacc[m][r])));
        wk[(m * 16 + lg * 4 + r) * XSTR + na] = f2b(g);
      }
  }
  __syncthreads();

  int ocol[3];
  f32x4 macc[4][3];
#pragma unroll
  for (int i = 0; i < 3; ++i) {
    ocol[i] = (3 * wv + i) * 16 + l15;
    const float bb2 = b2[ocol[i]];
#pragma unroll
    for (int m = 0; m < 4; ++m) macc[m][i] = (f32x4){bb2, bb2, bb2, bb2};
  }
#pragma unroll
  for (int ks = 0; ks < 6; ++ks) {
    const int k0 = ks * 32 + lg * 8;
    s16x8 gf[4];
#pragma unroll
    for (int m = 0; m < 4; ++m)
      gf[m] = *(const s16x8*)&wk[(m * 16 + l15) * XSTR + k0];
#pragma unroll
    for (int i = 0; i < 3; ++i) {
      s16x8 wf = *(const s16x8*)&w2b[(size_t)ocol[i] * 192 + k0];
#pragma unroll
      for (int m = 0; m < 4; ++m) macc[m][i] = MFMA(gf[m], wf, macc[m][i]);
    }
  }
  __syncthreads();
#pragma unroll
  for (int m = 0; m < 4; ++m)
#pragma unroll
    for (int i = 0; i < 3; ++i)
#pragma unroll
      for (int r = 0; r < 4; ++r)
        wk[(m * 16 + lg * 4 + r) * XSTR + ocol[i]] = f2b(macc[m][i][r]);
  __syncthreads();

  float* obase = out + (size_t)bb * 192 * 16384 + (size_t)(wh * 8) * 128 + wwi * 8;
#pragma unroll
  for (int it = 0; it < 6; ++it) {
    int job = tid + 256 * it;
    int i = job / 192;
    int c = job - i * 192;
    float vals[8];
#pragma unroll
    for (int j = 0; j < 8; ++j) {
      const int t = i * 8 + j;
      vals[j] = b2f(yb[t * XSTR + c]) + b2f(wk[t * XSTR + c]);
    }
    float* dst = obase + (size_t)c * 16384 + i * 128;
    f32x4 o0 = {vals[0], vals[1], vals[2], vals[3]};
    f32x4 o1 = {vals[4], vals[5], vals[6], vals[7]};
    *(f32x4*)dst = o0;
    *(f32x4*)(dst + 4) = o1;
  }
}

// ---------------------------------------------------------------------------
extern "C" void kernel_launch(void* const* d_in, const int* in_sizes, int n_in,
                              void* d_out, int out_size, void* d_ws, size_t ws_size,
                              hipStream_t stream) {
  (void)in_sizes; (void)n_in; (void)out_size; (void)ws_size;
  const float* x          = (const float*)d_in[0];
  const float* qkv_w      = (const float*)d_in[1];
  const float* qkv_b      = (const float*)d_in[2];
  const float* proj_w     = (const float*)d_in[3];
  const float* proj_b     = (const float*)d_in[4];
  const float* mlp1_w     = (const float*)d_in[5];
  const float* mlp1_b     = (const float*)d_in[6];
  const float* mlp2_w     = (const float*)d_in[7];
  const float* mlp2_b     = (const float*)d_in[8];
  const float* bias_table = (const float*)d_in[9];
  const int*   rel_index  = (const int*)d_in[10];
  float* out = (float*)d_out;

  char* ws = (char*)d_ws;
  unsigned short* qkv_wb  = (unsigned short*)ws + WOFF_QKV;
  unsigned short* proj_wb = (unsigned short*)ws + WOFF_PROJ;
  unsigned short* mlp1_wb = (unsigned short*)ws + WOFF_MLP1;
  unsigned short* mlp2_wb = (unsigned short*)ws + WOFF_MLP2;
  float*          biasx   = (float*)(ws + WOFF_BIASX_BYTES);
  unsigned short* xw      = (unsigned short*)(ws + WOFF_XW_BYTES);   // xw, then y

  hipLaunchKernelGGL(prep_kernel, dim3(1024), dim3(256), 0, stream,
                     qkv_w, proj_w, mlp1_w, mlp2_w, bias_table, rel_index,
                     qkv_wb, proj_wb, mlp1_wb, mlp2_wb, biasx);
  hipLaunchKernelGGL(xpose_kernel, dim3(1024), dim3(256), 0, stream, x, xw);
  hipLaunchKernelGGL(attn_kernel, dim3(1024), dim3(768), 0, stream,
                     xw, qkv_wb, qkv_b, proj_wb, proj_b, biasx);
  hipLaunchKernelGGL(mlp_kernel, dim3(2048), dim3(256), 0, stream,
                     xw, mlp1_wb, mlp1_b, mlp2_wb, mlp2_b, out);
}

// Round 19
// 248.807 us; speedup vs baseline: 1.2903x; 1.2903x over previous
//
#include <hip/hip_runtime.h>

// ---------------------------------------------------------------------------
// Swin-style windowed MHA block, MI355X/gfx950.
// R19 = R17 resubmitted (3rd attempt; broker containers kept dying).
// R17: fixes R16's 5.4x write amplification (271MB vs 50MB logical) -- the
// global in-place y RMW (8B scattered stores at 384B stride) is replaced by:
// stage xa from xw (contiguous) -> LDS, QKV A-frags from LDS, residual RMW
// in LDS, coalesced u16x8 copy back to xw. 3 barriers. LDS 147.5KB.
//   prep  : weights->bf16 + biasx gather.
//   xpose : x (BCHW f32) -> xw[2048][64][192] bf16.
//   attn  : stage xa -> QKV -> scores -> softmax -> PV -> AO(LDS) -> [B1]
//           -> proj -> y=x+proj in LDS -> [B2] -> coalesced copy to xw.
//   mlp   : R8-proven kernel, reads y (=xw), writes out fp32.
// ---------------------------------------------------------------------------

typedef short          s16x8 __attribute__((ext_vector_type(8)));
typedef unsigned short u16x4 __attribute__((ext_vector_type(4)));
typedef unsigned short u16x8 __attribute__((ext_vector_type(8)));
typedef float          f32x4 __attribute__((ext_vector_type(4)));

#define MFMA(A, B, C) __builtin_amdgcn_mfma_f32_16x16x32_bf16((A), (B), (C), 0, 0, 0)

__device__ __forceinline__ unsigned short f2b(float f) {
  unsigned x = __float_as_uint(f);
  x = (x + 0x7FFFu + ((x >> 16) & 1u)) >> 16;   // RNE
  return (unsigned short)x;
}
__device__ __forceinline__ float b2f(unsigned short u) {
  return __uint_as_float(((unsigned)u) << 16);
}
__device__ __forceinline__ u16x4 pk4(f32x4 v) {
  u16x4 r;
  r[0] = f2b(v[0]); r[1] = f2b(v[1]); r[2] = f2b(v[2]); r[3] = f2b(v[3]);
  return r;
}

// [64][32] tiles (Q,K,P-half,AO): 16B-chunk XOR keyed on (t>>1)&3
__device__ __forceinline__ int swz32(int t, int c) {
  return t * 32 + ((((c >> 3) ^ (t >> 1)) & 3) << 3) + (c & 7);
}
// Vt [32][64]: chunk XOR keyed on (d + (d>>3)) & 7
__device__ __forceinline__ int swzV(int d, int t) {
  return d * 64 + ((((t >> 3) ^ (d + (d >> 3))) & 7) << 3) + (t & 7);
}
// xa [64][192] unpadded: bijective chunk XOR keyed on t&7
__device__ __forceinline__ int xsw(int t, int c) {
  return t * 192 + (((c >> 3) ^ (t & 7)) << 3) + (c & 7);
}

#define XSTR   200      // mlp LDS row stride (unchanged, proven)
#define QSCALE 0.17677669529663687f

// workspace offsets
#define WOFF_QKV   0            // u16 elems
#define WOFF_PROJ  110592
#define WOFF_MLP1  147456
#define WOFF_MLP2  221184
#define WOFF_BIASX_BYTES 516096               // float[4096] -> ends 532480
#define WOFF_XW_BYTES    532480               // u16[2048*64*192] (xw, then y in place)

// ---------------------------------------------------------------------------
__global__ void prep_kernel(const float* __restrict__ qkv_w,
                            const float* __restrict__ proj_w,
                            const float* __restrict__ mlp1_w,
                            const float* __restrict__ mlp2_w,
                            const float* __restrict__ bias_table,
                            const int*   __restrict__ rel_index,
                            unsigned short* __restrict__ qkv_wb,
                            unsigned short* __restrict__ proj_wb,
                            unsigned short* __restrict__ mlp1_wb,
                            unsigned short* __restrict__ mlp2_wb,
                            float* __restrict__ biasx) {
  int j = blockIdx.x * 256 + threadIdx.x;   // 262144 jobs
  if (j < 110592) {
    float v = qkv_w[j];
    if (j < 36864) v *= QSCALE;
    qkv_wb[j] = f2b(v);
  } else if (j < 147456) {
    proj_wb[j - 110592] = f2b(proj_w[j - 110592]);
  } else if (j < 221184) {
    mlp1_wb[j - 147456] = f2b(mlp1_w[j - 147456]);
  } else if (j < 258048) {
    mlp2_wb[j - 221184] = f2b(mlp2_w[j - 221184]);
  } else {
    int e = j - 258048;                     // 0..4095
    int l = e >> 6, v = e & 63;
    int tm = v >> 4, tn = (v >> 2) & 3, r = v & 3;
    int q = tn * 16 + (l & 15);
    int k = tm * 16 + (l >> 4) * 4 + r;
    biasx[e] = bias_table[rel_index[q * 64 + k]];
  }
}

// ---------------------------------------------------------------------------
// x [B=8][C=192][H=128][W=128] f32  ->  xw [2048][64][192] bf16
#define TSTR 129
__global__ __launch_bounds__(256) void xpose_kernel(
    const float* __restrict__ x, unsigned short* __restrict__ xw) {
  __shared__ unsigned short tb[192 * TSTR];  // 49536 B
  const int tid = threadIdx.x;
  const int s   = ((blockIdx.x & 7) << 7) | (blockIdx.x >> 3);  // XCD swizzle
  const int b   = s >> 7;
  const int hr  = s & 127;
  const float* xrow = x + (size_t)b * 192 * 16384 + (size_t)hr * 128;

  // stage: 192 c x 4 wseg (32 floats each) = 768 jobs
#pragma unroll
  for (int it = 0; it < 3; ++it) {
    int job = tid + 256 * it;
    int c = job >> 2, wseg = job & 3;
    const float* src = xrow + (size_t)c * 16384 + wseg * 32;
    unsigned short* dst = &tb[c * TSTR + wseg * 32];
#pragma unroll
    for (int q = 0; q < 8; ++q) {
      f32x4 v = *(const f32x4*)(src + q * 4);
      u16x4 p; p[0] = f2b(v[0]); p[1] = f2b(v[1]); p[2] = f2b(v[2]); p[3] = f2b(v[3]);
      *(u16x4*)&dst[q * 4] = p;
    }
  }
  __syncthreads();

  // write: 16 wwi x 8 w' x 24 cseg = 3072 jobs, 16B contiguous runs
  const int winb = b * 256 + (hr >> 3) * 16;
  const int i = hr & 7;
#pragma unroll
  for (int it = 0; it < 12; ++it) {
    int job = tid + 256 * it;
    int wwi = job / 192;
    int rem = job - wwi * 192;
    int t7 = rem / 24;
    int cseg = rem - t7 * 24;
    u16x8 v;
#pragma unroll
    for (int jj = 0; jj < 8; ++jj)
      v[jj] = tb[(cseg * 8 + jj) * TSTR + wwi * 8 + t7];
    unsigned short* dst = xw + (size_t)(winb + wwi) * 12288 + (i * 8 + t7) * 192 + cseg * 8;
    *(u16x8*)dst = v;
  }
}

// ---------------------------------------------------------------------------
// 768 thr = 2 windows x 6 heads. 3 barriers: stage / AO / y-copyout.
__global__ __launch_bounds__(768, 3) void attn_kernel(
    unsigned short* __restrict__ xw,   // in: xw; out: y (coalesced writeback)
    const unsigned short* __restrict__ qkv_wb, const float* __restrict__ qkv_b,
    const unsigned short* __restrict__ proj_wb, const float* __restrict__ proj_b,
    const float* __restrict__ biasx) {
  __shared__ __align__(16) unsigned short sm[24576 + 12 * 4096];  // 147456 B

  const int tid  = threadIdx.x;
  const int lane = tid & 63;
  const int wv   = tid >> 6;          // 0..11
  const int wid  = (wv >= 6) ? 1 : 0;
  const int hd   = wv - wid * 6;
  const int l15  = lane & 15;
  const int lg   = lane >> 4;
  const int pair = ((blockIdx.x & 7) << 7) | (blockIdx.x >> 3);  // XCD swizzle
  const int wins0 = pair * 2;
  const int oQ   = hd * 32;

  // ---- stage both windows from xw: fully contiguous u16x8 reads ----
#pragma unroll
  for (int it = 0; it < 4; ++it) {
    int job = tid + 768 * it;          // 0..3071 vec8 jobs
    int wi = job / 1536;
    int j  = job - wi * 1536;          // vec8 index in window
    int t  = j / 24;
    int c  = (j - t * 24) * 8;
    u16x8 v = *(const u16x8*)&xw[(size_t)(wins0 + wi) * 12288 + (size_t)j * 8];
    *(u16x8*)&sm[wi * 12288 + xsw(t, c)] = v;
  }
  __syncthreads();  // B0: xa staged

  unsigned short* xa  = sm + wid * 12288;            // [64][192] xsw
  unsigned short* hb  = sm + 24576 + (wid * 6 + hd) * 4096;
  unsigned short* R0  = hb;            // Q -> Phalf -> AO (4KB, [64][32] swz32)
  unsigned short* R1  = hb + 2048;     // K -> Vt          (4KB)

  // ---------------- QKV: Q^T,K^T = mfma(w, x);  V = mfma(x, w) ----------------
  f32x4 accqT[2][4], acckT[2][4], accv[4][2];
#pragma unroll
  for (int m = 0; m < 2; ++m) {
    f32x4 bq4 = *(const f32x4*)&qkv_b[oQ + m * 16 + lg * 4];
    f32x4 bk4 = *(const f32x4*)&qkv_b[192 + oQ + m * 16 + lg * 4];
#pragma unroll
    for (int tn = 0; tn < 4; ++tn) {
      accqT[m][tn] = bq4 * QSCALE;
      acckT[m][tn] = bk4;
    }
  }
#pragma unroll
  for (int nt = 0; nt < 2; ++nt) {
    const float bv = qkv_b[384 + oQ + nt * 16 + l15];
#pragma unroll
    for (int mt = 0; mt < 4; ++mt) accv[mt][nt] = (f32x4){bv, bv, bv, bv};
  }
#pragma unroll
  for (int ks = 0; ks < 6; ++ks) {
    const int k0 = ks * 32 + lg * 8;
    s16x8 bf[4];
#pragma unroll
    for (int tn = 0; tn < 4; ++tn)
      bf[tn] = *(const s16x8*)&xa[xsw(tn * 16 + l15, k0)];
    s16x8 wq[2], wk[2], wvv[2];
#pragma unroll
    for (int m = 0; m < 2; ++m) {
      wq[m]  = *(const s16x8*)&qkv_wb[(size_t)(oQ + m * 16 + l15) * 192 + k0];
      wk[m]  = *(const s16x8*)&qkv_wb[(size_t)(192 + oQ + m * 16 + l15) * 192 + k0];
      wvv[m] = *(const s16x8*)&qkv_wb[(size_t)(384 + oQ + m * 16 + l15) * 192 + k0];
    }
#pragma unroll
    for (int m = 0; m < 2; ++m)
#pragma unroll
      for (int tn = 0; tn < 4; ++tn) {
        accqT[m][tn] = MFMA(wq[m], bf[tn], accqT[m][tn]);
        acckT[m][tn] = MFMA(wk[m], bf[tn], acckT[m][tn]);
      }
#pragma unroll
    for (int mt = 0; mt < 4; ++mt)
#pragma unroll
      for (int nt = 0; nt < 2; ++nt)
        accv[mt][nt] = MFMA(bf[mt], wvv[nt], accv[mt][nt]);
  }
  // Q,K stores: C[d][t] regs run along d -> u16x4 into row-major [t][d]
#pragma unroll
  for (int m = 0; m < 2; ++m)
#pragma unroll
    for (int tn = 0; tn < 4; ++tn) {
      const int t = tn * 16 + l15, d0 = m * 16 + lg * 4;
      *(u16x4*)&R0[swz32(t, d0)] = pk4(accqT[m][tn]);
      *(u16x4*)&R1[swz32(t, d0)] = pk4(acckT[m][tn]);
    }
  u16x4 vreg[4][2];
#pragma unroll
  for (int mt = 0; mt < 4; ++mt)
#pragma unroll
    for (int nt = 0; nt < 2; ++nt)
      vreg[mt][nt] = pk4(accv[mt][nt]);

  // ---------------- scores^T = mfma(K, Q) + bias ----------------
  const float* bxp = biasx + lane * 64;
  s16x8 kf[4], qf[4];
#pragma unroll
  for (int tm = 0; tm < 4; ++tm)
    kf[tm] = *(const s16x8*)&R1[swz32(tm * 16 + l15, lg * 8)];
#pragma unroll
  for (int tn = 0; tn < 4; ++tn)
    qf[tn] = *(const s16x8*)&R0[swz32(tn * 16 + l15, lg * 8)];
  // Vt over K (in-wave DS order: writes cannot pass the kf reads)
#pragma unroll
  for (int mt = 0; mt < 4; ++mt)
#pragma unroll
    for (int nt = 0; nt < 2; ++nt)
      *(u16x4*)&R1[swzV(nt * 16 + l15, mt * 16 + lg * 4)] = vreg[mt][nt];

  f32x4 sc[4][4];
#pragma unroll
  for (int tm = 0; tm < 4; ++tm)
#pragma unroll
    for (int tn = 0; tn < 4; ++tn) {
      f32x4 bfr = *(const f32x4*)&bxp[tm * 16 + tn * 4];
      sc[tm][tn] = MFMA(kf[tm], qf[tn], bfr);
    }
  // softmax over keys
#pragma unroll
  for (int tn = 0; tn < 4; ++tn) {
    float mx = sc[0][tn][0];
#pragma unroll
    for (int tm = 0; tm < 4; ++tm)
#pragma unroll
      for (int r = 0; r < 4; ++r) mx = fmaxf(mx, sc[tm][tn][r]);
    mx = fmaxf(mx, __shfl_xor(mx, 16));
    mx = fmaxf(mx, __shfl_xor(mx, 32));
    float sum = 0.f;
#pragma unroll
    for (int tm = 0; tm < 4; ++tm)
#pragma unroll
      for (int r = 0; r < 4; ++r) {
        float e = __expf(sc[tm][tn][r] - mx);
        sc[tm][tn][r] = e;
        sum += e;
      }
    sum += __shfl_xor(sum, 16);
    sum += __shfl_xor(sum, 32);
    const float inv = 1.0f / sum;
#pragma unroll
    for (int tm = 0; tm < 4; ++tm)
#pragma unroll
      for (int r = 0; r < 4; ++r) sc[tm][tn][r] *= inv;
  }

  // ---------------- PV as out^T = mfma(Vt, P), P in halves over R0 ----------------
  f32x4 oT[2][4];
#pragma unroll
  for (int m = 0; m < 2; ++m)
#pragma unroll
    for (int tn = 0; tn < 4; ++tn) oT[m][tn] = (f32x4){0.f, 0.f, 0.f, 0.f};
#pragma unroll
  for (int half = 0; half < 2; ++half) {
#pragma unroll
    for (int tm = 0; tm < 2; ++tm)
#pragma unroll
      for (int tn = 0; tn < 4; ++tn)
        *(u16x4*)&R0[swz32(tn * 16 + l15, tm * 16 + lg * 4)] =
            pk4(sc[half * 2 + tm][tn]);
    s16x8 bp[4], av[2];
#pragma unroll
    for (int tn = 0; tn < 4; ++tn)
      bp[tn] = *(const s16x8*)&R0[swz32(tn * 16 + l15, lg * 8)];
#pragma unroll
    for (int m = 0; m < 2; ++m)
      av[m] = *(const s16x8*)&R1[swzV(m * 16 + l15, half * 32 + lg * 8)];
#pragma unroll
    for (int m = 0; m < 2; ++m)
#pragma unroll
      for (int tn = 0; tn < 4; ++tn)
        oT[m][tn] = MFMA(av[m], bp[tn], oT[m][tn]);
  }
  // AO store into R0 (LDS): C[d][t] -> u16x4 into [t][d]
#pragma unroll
  for (int m = 0; m < 2; ++m)
#pragma unroll
    for (int tn = 0; tn < 4; ++tn)
      *(u16x4*)&R0[swz32(tn * 16 + l15, m * 16 + lg * 4)] = pk4(oT[m][tn]);
  __syncthreads();  // B1: all heads' AO visible (also: all xa reads done)

  // ---------------- proj^T = mfma(Wp, AO) + residual RMW in LDS ----------------
  f32x4 pjT[2][4];
#pragma unroll
  for (int m = 0; m < 2; ++m) {
    f32x4 bp4 = *(const f32x4*)&proj_b[oQ + m * 16 + lg * 4];
#pragma unroll
    for (int tn = 0; tn < 4; ++tn) pjT[m][tn] = bp4;
  }
#pragma unroll
  for (int hh = 0; hh < 6; ++hh) {
    const unsigned short* aoh = sm + 24576 + (wid * 6 + hh) * 4096;
    s16x8 aa[4];
#pragma unroll
    for (int tn = 0; tn < 4; ++tn)
      aa[tn] = *(const s16x8*)&aoh[swz32(tn * 16 + l15, lg * 8)];
    s16x8 wp[2];
#pragma unroll
    for (int m = 0; m < 2; ++m)
      wp[m] = *(const s16x8*)&proj_wb[(size_t)(oQ + m * 16 + l15) * 192 + hh * 32 + lg * 8];
#pragma unroll
    for (int m = 0; m < 2; ++m)
#pragma unroll
      for (int tn = 0; tn < 4; ++tn)
        pjT[m][tn] = MFMA(wp[m], aa[tn], pjT[m][tn]);
  }
  // y = x + proj: lane-private u16x4 RMW in LDS xa (reads all done pre-B1)
#pragma unroll
  for (int m = 0; m < 2; ++m)
#pragma unroll
    for (int tn = 0; tn < 4; ++tn) {
      const int t = tn * 16 + l15, o0 = oQ + m * 16 + lg * 4;
      const int ad = xsw(t, o0);
      u16x4 old = *(const u16x4*)&xa[ad];
      f32x4 s;
#pragma unroll
      for (int r = 0; r < 4; ++r) s[r] = pjT[m][tn][r] + b2f(old[r]);
      *(u16x4*)&xa[ad] = pk4(s);
    }
  __syncthreads();  // B2: y complete for both windows

  // ---- coalesced copy y (LDS, de-swizzled) -> xw ----
#pragma unroll
  for (int it = 0; it < 4; ++it) {
    int job = tid + 768 * it;
    int wi = job / 1536;
    int j  = job - wi * 1536;
    int t  = j / 24;
    int c  = (j - t * 24) * 8;
    u16x8 v = *(const u16x8*)&sm[wi * 12288 + xsw(t, c)];
    *(u16x8*)&xw[(size_t)(wins0 + wi) * 12288 + (size_t)j * 8] = v;
  }
}

// ---------------------------------------------------------------------------
__global__ __launch_bounds__(256, 4) void mlp_kernel(
    const unsigned short* __restrict__ y_win,
    const unsigned short* __restrict__ w1b, const float* __restrict__ b1,
    const unsigned short* __restrict__ w2b, const float* __restrict__ b2,
    float* __restrict__ out) {
  __shared__ __align__(16) unsigned short sm2[2 * 64 * XSTR];
  unsigned short* yb = sm2;
  unsigned short* wk = sm2 + 64 * XSTR;

  const int tid  = threadIdx.x;
  const int lane = tid & 63;
  const int wv   = tid >> 6;
  const int l15  = lane & 15;
  const int lg   = lane >> 4;
  const int win  = ((blockIdx.x & 7) << 8) | (blockIdx.x >> 3);
  const int bb   = win >> 8;
  const int wh   = (win >> 4) & 15;
  const int wwi  = win & 15;

  const unsigned short* ywp = y_win + (size_t)win * 12288;
#pragma unroll
  for (int it = 0; it < 6; ++it) {
    int job = tid + 256 * it;
    int t = job / 24;
    int seg = job - t * 24;
    *(u16x8*)&yb[t * XSTR + seg * 8] = *(const u16x8*)&ywp[(size_t)job * 8];
  }
  __syncthreads();

#pragma unroll
  for (int i = 0; i < 3; ++i) {
    const int na = (3 * wv + i) * 16 + l15;
    const int nb = na + 192;
    f32x4 aacc[4], bacc[4];
    const float ba = b1[na], bbv = b1[nb];
#pragma unroll
    for (int m = 0; m < 4; ++m) {
      aacc[m] = (f32x4){ba, ba, ba, ba};
      bacc[m] = (f32x4){bbv, bbv, bbv, bbv};
    }
#pragma unroll
    for (int ks = 0; ks < 6; ++ks) {
      const int k0 = ks * 32 + lg * 8;
      s16x8 af[4];
#pragma unroll
      for (int m = 0; m < 4; ++m)
        af[m] = *(const s16x8*)&yb[(m * 16 + l15) * XSTR + k0];
      s16x8 wa = *(const s16x8*)&w1b[(size_t)na * 192 + k0];
      s16x8 wb = *(const s16x8*)&w1b[(size_t)nb * 192 + k0];
#pragma unroll
      for (int m = 0; m < 4; ++m) {
        aacc[m] = MFMA(af[m], wa, aacc[m]);
        bacc[m] = MFMA(af[m], wb, bacc[m]);
      }
    }
#pragma unroll
    for (int m = 0; m < 4; ++m)
#pragma unroll
      for (int r = 0; r < 4; ++r) {
        const float g = aacc[m][r] * (1.0f / (1.0f + __expf(-bacc[m][r])));
        wk[(m * 16 + lg * 4 + r) * XSTR + na] = f2b(g);
      }
  }
  __syncthreads();

  int ocol[3];
  f32x4 macc[4][3];
#pragma unroll
  for (int i = 0; i < 3; ++i) {
    ocol[i] = (3 * wv + i) * 16 + l15;
    const float bb2 = b2[ocol[i]];
#pragma unroll
    for (int m = 0; m < 4; ++m) macc[m][i] = (f32x4){bb2, bb2, bb2, bb2};
  }
#pragma unroll
  for (int ks = 0; ks < 6; ++ks) {
    const int k0 = ks * 32 + lg * 8;
    s16x8 gf[4];
#pragma unroll
    for (int m = 0; m < 4; ++m)
      gf[m] = *(const s16x8*)&wk[(m * 16 + l15) * XSTR + k0];
#pragma unroll
    for (int i = 0; i < 3; ++i) {
      s16x8 wf = *(const s16x8*)&w2b[(size_t)ocol[i] * 192 + k0];
#pragma unroll
      for (int m = 0; m < 4; ++m) macc[m][i] = MFMA(gf[m], wf, macc[m][i]);
    }
  }
  __syncthreads();
#pragma unroll
  for (int m = 0; m < 4; ++m)
#pragma unroll
    for (int i = 0; i < 3; ++i)
#pragma unroll
      for (int r = 0; r < 4; ++r)
        wk[(m * 16 + lg * 4 + r) * XSTR + ocol[i]] = f2b(macc[m][i][r]);
  __syncthreads();

  float* obase = out + (size_t)bb * 192 * 16384 + (size_t)(wh * 8) * 128 + wwi * 8;
#pragma unroll
  for (int it = 0; it < 6; ++it) {
    int job = tid + 256 * it;
    int i = job / 192;
    int c = job - i * 192;
    float vals[8];
#pragma unroll
    for (int j = 0; j < 8; ++j) {
      const int t = i * 8 + j;
      vals[j] = b2f(yb[t * XSTR + c]) + b2f(wk[t * XSTR + c]);
    }
    float* dst = obase + (size_t)c * 16384 + i * 128;
    f32x4 o0 = {vals[0], vals[1], vals[2], vals[3]};
    f32x4 o1 = {vals[4], vals[5], vals[6], vals[7]};
    *(f32x4*)dst = o0;
    *(f32x4*)(dst + 4) = o1;
  }
}

// ---------------------------------------------------------------------------
extern "C" void kernel_launch(void* const* d_in, const int* in_sizes, int n_in,
                              void* d_out, int out_size, void* d_ws, size_t ws_size,
                              hipStream_t stream) {
  (void)in_sizes; (void)n_in; (void)out_size; (void)ws_size;
  const float* x          = (const float*)d_in[0];
  const float* qkv_w      = (const float*)d_in[1];
  const float* qkv_b      = (const float*)d_in[2];
  const float* proj_w     = (const float*)d_in[3];
  const float* proj_b     = (const float*)d_in[4];
  const float* mlp1_w     = (const float*)d_in[5];
  const float* mlp1_b     = (const float*)d_in[6];
  const float* mlp2_w     = (const float*)d_in[7];
  const float* mlp2_b     = (const float*)d_in[8];
  const float* bias_table = (const float*)d_in[9];
  const int*   rel_index  = (const int*)d_in[10];
  float* out = (float*)d_out;

  char* ws = (char*)d_ws;
  unsigned short* qkv_wb  = (unsigned short*)ws + WOFF_QKV;
  unsigned short* proj_wb = (unsigned short*)ws + WOFF_PROJ;
  unsigned short* mlp1_wb = (unsigned short*)ws + WOFF_MLP1;
  unsigned short* mlp2_wb = (unsigned short*)ws + WOFF_MLP2;
  float*          biasx   = (float*)(ws + WOFF_BIASX_BYTES);
  unsigned short* xw      = (unsigned short*)(ws + WOFF_XW_BYTES);   // xw, then y

  hipLaunchKernelGGL(prep_kernel, dim3(1024), dim3(256), 0, stream,
                     qkv_w, proj_w, mlp1_w, mlp2_w, bias_table, rel_index,
                     qkv_wb, proj_wb, mlp1_wb, mlp2_wb, biasx);
  hipLaunchKernelGGL(xpose_kernel, dim3(1024), dim3(256), 0, stream, x, xw);
  hipLaunchKernelGGL(attn_kernel, dim3(1024), dim3(768), 0, stream,
                     xw, qkv_wb, qkv_b, proj_wb, proj_b, biasx);
  hipLaunchKernelGGL(mlp_kernel, dim3(2048), dim3(256), 0, stream,
                     xw, mlp1_wb, mlp1_b, mlp2_wb, mlp2_b, out);
}

// Round 20
// 241.559 us; speedup vs baseline: 1.3291x; 1.0300x over previous
//
#include <hip/hip_runtime.h>

// ---------------------------------------------------------------------------
// Swin-style windowed MHA block, MI355X/gfx950.
// R20: (a) xpose kernel deleted -- attn stages both windows straight from
// BCHW f32 x (32B-coalesced reads, bank-spread scatter via re-keyed xsw);
// (b) rel-pos bias moved off the MFMA C-operand chain: prep emits bf16
// bias in [e][lane] layout, attn stages it to LDS (8KB) and adds post-MFMA
// in VALU (conflict-free ds_read_u16, overlaps MFMA issue).
//   prep : weights->bf16 + bias gather (bf16, transposed layout).
//   attn : stage bias+x -> QKV -> scores(+bias) -> softmax -> PV -> AO(LDS)
//          -> [B1] -> proj -> y=x+proj in LDS -> [B2] -> coalesced y -> yw.
//   mlp  : R8-proven kernel, reads yw, writes out fp32.
// LDS 155648B; ws 50.9MB (proven).
// ---------------------------------------------------------------------------

typedef short          s16x8 __attribute__((ext_vector_type(8)));
typedef unsigned short u16x4 __attribute__((ext_vector_type(4)));
typedef unsigned short u16x8 __attribute__((ext_vector_type(8)));
typedef float          f32x4 __attribute__((ext_vector_type(4)));

#define MFMA(A, B, C) __builtin_amdgcn_mfma_f32_16x16x32_bf16((A), (B), (C), 0, 0, 0)

__device__ __forceinline__ unsigned short f2b(float f) {
  unsigned x = __float_as_uint(f);
  x = (x + 0x7FFFu + ((x >> 16) & 1u)) >> 16;   // RNE
  return (unsigned short)x;
}
__device__ __forceinline__ float b2f(unsigned short u) {
  return __uint_as_float(((unsigned)u) << 16);
}
__device__ __forceinline__ u16x4 pk4(f32x4 v) {
  u16x4 r;
  r[0] = f2b(v[0]); r[1] = f2b(v[1]); r[2] = f2b(v[2]); r[3] = f2b(v[3]);
  return r;
}

// [64][32] tiles (Q,K,P-half,AO): 16B-chunk XOR keyed on (t>>1)&3
__device__ __forceinline__ int swz32(int t, int c) {
  return t * 32 + ((((c >> 3) ^ (t >> 1)) & 3) << 3) + (c & 7);
}
// Vt [32][64]: chunk XOR keyed on (d + (d>>3)) & 7
__device__ __forceinline__ int swzV(int d, int t) {
  return d * 64 + ((((t >> 3) ^ (d + (d >> 3))) & 7) << 3) + (t & 7);
}
// xa [64][192] unpadded: bijective chunk XOR keyed on (t ^ (t>>3)) & 7
// (staging scatter: banks (r^i)*4+(c>>1) -> all 32, 2 lanes each = free)
__device__ __forceinline__ int xsw(int t, int c) {
  return t * 192 + ((((c >> 3) ^ ((t ^ (t >> 3)) & 7))) << 3) + (c & 7);
}

#define XSTR   200      // mlp LDS row stride (proven)
#define QSCALE 0.17677669529663687f

// LDS element offsets inside attn
#define L_BIAS 0        // u16[4096]  bias [e][lane]
#define L_XA   4096     // u16[2*12288] two windows
#define L_HD   28672    // u16[12*4096] head regions

// workspace offsets
#define WOFF_QKV   0            // u16 elems
#define WOFF_PROJ  110592
#define WOFF_MLP1  147456
#define WOFF_MLP2  221184
#define WOFF_BIASB_BYTES 516096               // u16[4096]
#define WOFF_YW_BYTES    532480               // u16[2048*64*192] (y only)

// ---------------------------------------------------------------------------
__global__ void prep_kernel(const float* __restrict__ qkv_w,
                            const float* __restrict__ proj_w,
                            const float* __restrict__ mlp1_w,
                            const float* __restrict__ mlp2_w,
                            const float* __restrict__ bias_table,
                            const int*   __restrict__ rel_index,
                            unsigned short* __restrict__ qkv_wb,
                            unsigned short* __restrict__ proj_wb,
                            unsigned short* __restrict__ mlp1_wb,
                            unsigned short* __restrict__ mlp2_wb,
                            unsigned short* __restrict__ biasb) {
  int j = blockIdx.x * 256 + threadIdx.x;   // 262144 jobs
  if (j < 110592) {
    float v = qkv_w[j];
    if (j < 36864) v *= QSCALE;
    qkv_wb[j] = f2b(v);
  } else if (j < 147456) {
    proj_wb[j - 110592] = f2b(proj_w[j - 110592]);
  } else if (j < 221184) {
    mlp1_wb[j - 147456] = f2b(mlp1_w[j - 147456]);
  } else if (j < 258048) {
    mlp2_wb[j - 221184] = f2b(mlp2_w[j - 221184]);
  } else {
    int e = j - 258048;                     // 0..4095 = v*64 + l
    int v = e >> 6, l = e & 63;
    int tm = v >> 4, tn = (v >> 2) & 3, r = v & 3;
    int q = tn * 16 + (l & 15);
    int k = tm * 16 + (l >> 4) * 4 + r;
    biasb[e] = f2b(bias_table[rel_index[q * 64 + k]]);
  }
}

// ---------------------------------------------------------------------------
// 768 thr = 2 windows x 6 heads. 3 barriers: stage / AO / y-copyout.
__global__ __launch_bounds__(768, 3) void attn_kernel(
    const float* __restrict__ x,
    const unsigned short* __restrict__ qkv_wb, const float* __restrict__ qkv_b,
    const unsigned short* __restrict__ proj_wb, const float* __restrict__ proj_b,
    const unsigned short* __restrict__ biasb,
    unsigned short* __restrict__ yw) {
  __shared__ __align__(16) unsigned short sm[77824];  // 155648 B

  const int tid  = threadIdx.x;
  const int lane = tid & 63;
  const int wv   = tid >> 6;          // 0..11
  const int wid  = (wv >= 6) ? 1 : 0;
  const int hd   = wv - wid * 6;
  const int l15  = lane & 15;
  const int lg   = lane >> 4;
  const int pair = ((blockIdx.x & 7) << 7) | (blockIdx.x >> 3);  // XCD swizzle
  const int wins0 = pair * 2;
  const int oQ   = hd * 32;

  // ---- stage bias (8KB) ----
  if (tid < 512)
    *(u16x8*)&sm[L_BIAS + tid * 8] = *(const u16x8*)&biasb[tid * 8];

  // ---- stage both windows from BCHW f32 x (32B reads, swizzled scatter) ----
  const float* xwb[2];
#pragma unroll
  for (int wi = 0; wi < 2; ++wi) {
    const int w = wins0 + wi;
    xwb[wi] = x + (size_t)(w >> 8) * 192 * 16384
                + (size_t)(((w >> 4) & 15) * 8) * 128 + (w & 15) * 8;
  }
#pragma unroll
  for (int it = 0; it < 4; ++it) {
    int job = tid + 768 * it;          // 3072 jobs = 2 wi x (192c x 8i)
    int wi = job / 1536;
    int j  = job - wi * 1536;
    int c = j >> 3, i = j & 7;
    const float* src = xwb[wi] + (size_t)c * 16384 + i * 128;
    f32x4 v0 = *(const f32x4*)(src);
    f32x4 v1 = *(const f32x4*)(src + 4);
    unsigned short* xa_ = sm + L_XA + wi * 12288;
#pragma unroll
    for (int r = 0; r < 4; ++r) xa_[xsw(i * 8 + r, c)] = f2b(v0[r]);
#pragma unroll
    for (int r = 0; r < 4; ++r) xa_[xsw(i * 8 + 4 + r, c)] = f2b(v1[r]);
  }
  __syncthreads();  // B0: bias + xa staged

  unsigned short* xa  = sm + L_XA + wid * 12288;      // [64][192] xsw
  unsigned short* hb  = sm + L_HD + (wid * 6 + hd) * 4096;
  unsigned short* R0  = hb;            // Q -> Phalf -> AO (4KB, swz32)
  unsigned short* R1  = hb + 2048;     // K -> Vt          (4KB)

  // ---------------- QKV: Q^T,K^T = mfma(w, x);  V = mfma(x, w) ----------------
  f32x4 accqT[2][4], acckT[2][4], accv[4][2];
#pragma unroll
  for (int m = 0; m < 2; ++m) {
    f32x4 bq4 = *(const f32x4*)&qkv_b[oQ + m * 16 + lg * 4];
    f32x4 bk4 = *(const f32x4*)&qkv_b[192 + oQ + m * 16 + lg * 4];
#pragma unroll
    for (int tn = 0; tn < 4; ++tn) {
      accqT[m][tn] = bq4 * QSCALE;
      acckT[m][tn] = bk4;
    }
  }
#pragma unroll
  for (int nt = 0; nt < 2; ++nt) {
    const float bv = qkv_b[384 + oQ + nt * 16 + l15];
#pragma unroll
    for (int mt = 0; mt < 4; ++mt) accv[mt][nt] = (f32x4){bv, bv, bv, bv};
  }
#pragma unroll
  for (int ks = 0; ks < 6; ++ks) {
    const int k0 = ks * 32 + lg * 8;
    s16x8 bf[4];
#pragma unroll
    for (int tn = 0; tn < 4; ++tn)
      bf[tn] = *(const s16x8*)&xa[xsw(tn * 16 + l15, k0)];
    s16x8 wq[2], wk[2], wvv[2];
#pragma unroll
    for (int m = 0; m < 2; ++m) {
      wq[m]  = *(const s16x8*)&qkv_wb[(size_t)(oQ + m * 16 + l15) * 192 + k0];
      wk[m]  = *(const s16x8*)&qkv_wb[(size_t)(192 + oQ + m * 16 + l15) * 192 + k0];
      wvv[m] = *(const s16x8*)&qkv_wb[(size_t)(384 + oQ + m * 16 + l15) * 192 + k0];
    }
#pragma unroll
    for (int m = 0; m < 2; ++m)
#pragma unroll
      for (int tn = 0; tn < 4; ++tn) {
        accqT[m][tn] = MFMA(wq[m], bf[tn], accqT[m][tn]);
        acckT[m][tn] = MFMA(wk[m], bf[tn], acckT[m][tn]);
      }
#pragma unroll
    for (int mt = 0; mt < 4; ++mt)
#pragma unroll
      for (int nt = 0; nt < 2; ++nt)
        accv[mt][nt] = MFMA(bf[mt], wvv[nt], accv[mt][nt]);
  }
  // Q,K stores: C[d][t] regs run along d -> u16x4 into row-major [t][d]
#pragma unroll
  for (int m = 0; m < 2; ++m)
#pragma unroll
    for (int tn = 0; tn < 4; ++tn) {
      const int t = tn * 16 + l15, d0 = m * 16 + lg * 4;
      *(u16x4*)&R0[swz32(t, d0)] = pk4(accqT[m][tn]);
      *(u16x4*)&R1[swz32(t, d0)] = pk4(acckT[m][tn]);
    }
  u16x4 vreg[4][2];
#pragma unroll
  for (int mt = 0; mt < 4; ++mt)
#pragma unroll
    for (int nt = 0; nt < 2; ++nt)
      vreg[mt][nt] = pk4(accv[mt][nt]);

  // ---------------- scores^T = mfma(K, Q); bias added post-MFMA ----------------
  s16x8 kf[4], qf[4];
#pragma unroll
  for (int tm = 0; tm < 4; ++tm)
    kf[tm] = *(const s16x8*)&R1[swz32(tm * 16 + l15, lg * 8)];
#pragma unroll
  for (int tn = 0; tn < 4; ++tn)
    qf[tn] = *(const s16x8*)&R0[swz32(tn * 16 + l15, lg * 8)];
  // Vt over K (in-wave DS order: writes cannot pass the kf reads)
#pragma unroll
  for (int mt = 0; mt < 4; ++mt)
#pragma unroll
    for (int nt = 0; nt < 2; ++nt)
      *(u16x4*)&R1[swzV(nt * 16 + l15, mt * 16 + lg * 4)] = vreg[mt][nt];

  const f32x4 z4 = {0.f, 0.f, 0.f, 0.f};
  f32x4 sc[4][4];
#pragma unroll
  for (int tm = 0; tm < 4; ++tm)
#pragma unroll
    for (int tn = 0; tn < 4; ++tn)
      sc[tm][tn] = MFMA(kf[tm], qf[tn], z4);
  // bias add: conflict-free ds_read_u16 from [e][lane] layout
#pragma unroll
  for (int tm = 0; tm < 4; ++tm)
#pragma unroll
    for (int tn = 0; tn < 4; ++tn)
#pragma unroll
      for (int r = 0; r < 4; ++r)
        sc[tm][tn][r] += b2f(sm[L_BIAS + ((tm * 16 + tn * 4 + r) << 6) + lane]);
  // softmax over keys
#pragma unroll
  for (int tn = 0; tn < 4; ++tn) {
    float mx = sc[0][tn][0];
#pragma unroll
    for (int tm = 0; tm < 4; ++tm)
#pragma unroll
      for (int r = 0; r < 4; ++r) mx = fmaxf(mx, sc[tm][tn][r]);
    mx = fmaxf(mx, __shfl_xor(mx, 16));
    mx = fmaxf(mx, __shfl_xor(mx, 32));
    float sum = 0.f;
#pragma unroll
    for (int tm = 0; tm < 4; ++tm)
#pragma unroll
      for (int r = 0; r < 4; ++r) {
        float e = __expf(sc[tm][tn][r] - mx);
        sc[tm][tn][r] = e;
        sum += e;
      }
    sum += __shfl_xor(sum, 16);
    sum += __shfl_xor(sum, 32);
    const float inv = 1.0f / sum;
#pragma unroll
    for (int tm = 0; tm < 4; ++tm)
#pragma unroll
      for (int r = 0; r < 4; ++r) sc[tm][tn][r] *= inv;
  }

  // ---------------- PV as out^T = mfma(Vt, P), P in halves over R0 ----------------
  f32x4 oT[2][4];
#pragma unroll
  for (int m = 0; m < 2; ++m)
#pragma unroll
    for (int tn = 0; tn < 4; ++tn) oT[m][tn] = z4;
#pragma unroll
  for (int half = 0; half < 2; ++half) {
#pragma unroll
    for (int tm = 0; tm < 2; ++tm)
#pragma unroll
      for (int tn = 0; tn < 4; ++tn)
        *(u16x4*)&R0[swz32(tn * 16 + l15, tm * 16 + lg * 4)] =
            pk4(sc[half * 2 + tm][tn]);
    s16x8 bp[4], av[2];
#pragma unroll
    for (int tn = 0; tn < 4; ++tn)
      bp[tn] = *(const s16x8*)&R0[swz32(tn * 16 + l15, lg * 8)];
#pragma unroll
    for (int m = 0; m < 2; ++m)
      av[m] = *(const s16x8*)&R1[swzV(m * 16 + l15, half * 32 + lg * 8)];
#pragma unroll
    for (int m = 0; m < 2; ++m)
#pragma unroll
      for (int tn = 0; tn < 4; ++tn)
        oT[m][tn] = MFMA(av[m], bp[tn], oT[m][tn]);
  }
  // AO store into R0 (LDS): C[d][t] -> u16x4 into [t][d]
#pragma unroll
  for (int m = 0; m < 2; ++m)
#pragma unroll
    for (int tn = 0; tn < 4; ++tn)
      *(u16x4*)&R0[swz32(tn * 16 + l15, m * 16 + lg * 4)] = pk4(oT[m][tn]);
  __syncthreads();  // B1: all heads' AO visible; all xa reads done

  // ---------------- proj^T = mfma(Wp, AO) + residual RMW in LDS ----------------
  f32x4 pjT[2][4];
#pragma unroll
  for (int m = 0; m < 2; ++m) {
    f32x4 bp4 = *(const f32x4*)&proj_b[oQ + m * 16 + lg * 4];
#pragma unroll
    for (int tn = 0; tn < 4; ++tn) pjT[m][tn] = bp4;
  }
#pragma unroll
  for (int hh = 0; hh < 6; ++hh) {
    const unsigned short* aoh = sm + L_HD + (wid * 6 + hh) * 4096;
    s16x8 aa[4];
#pragma unroll
    for (int tn = 0; tn < 4; ++tn)
      aa[tn] = *(const s16x8*)&aoh[swz32(tn * 16 + l15, lg * 8)];
    s16x8 wp[2];
#pragma unroll
    for (int m = 0; m < 2; ++m)
      wp[m] = *(const s16x8*)&proj_wb[(size_t)(oQ + m * 16 + l15) * 192 + hh * 32 + lg * 8];
#pragma unroll
    for (int m = 0; m < 2; ++m)
#pragma unroll
      for (int tn = 0; tn < 4; ++tn)
        pjT[m][tn] = MFMA(wp[m], aa[tn], pjT[m][tn]);
  }
  // y = x + proj: lane-private u16x4 RMW in LDS xa
#pragma unroll
  for (int m = 0; m < 2; ++m)
#pragma unroll
    for (int tn = 0; tn < 4; ++tn) {
      const int t = tn * 16 + l15, o0 = oQ + m * 16 + lg * 4;
      const int ad = xsw(t, o0);
      u16x4 old = *(const u16x4*)&xa[ad];
      f32x4 s;
#pragma unroll
      for (int r = 0; r < 4; ++r) s[r] = pjT[m][tn][r] + b2f(old[r]);
      *(u16x4*)&xa[ad] = pk4(s);
    }
  __syncthreads();  // B2: y complete for both windows

  // ---- coalesced copy y (LDS, de-swizzled) -> yw ----
#pragma unroll
  for (int it = 0; it < 4; ++it) {
    int job = tid + 768 * it;
    int wi = job / 1536;
    int j  = job - wi * 1536;
    int t  = j / 24;
    int c  = (j - t * 24) * 8;
    u16x8 v = *(const u16x8*)&sm[L_XA + wi * 12288 + xsw(t, c)];
    *(u16x8*)&yw[(size_t)(wins0 + wi) * 12288 + (size_t)j * 8] = v;
  }
}

// ---------------------------------------------------------------------------
__global__ __launch_bounds__(256, 4) void mlp_kernel(
    const unsigned short* __restrict__ y_win,
    const unsigned short* __restrict__ w1b, const float* __restrict__ b1,
    const unsigned short* __restrict__ w2b, const float* __restrict__ b2,
    float* __restrict__ out) {
  __shared__ __align__(16) unsigned short sm2[2 * 64 * XSTR];
  unsigned short* yb = sm2;
  unsigned short* wk = sm2 + 64 * XSTR;

  const int tid  = threadIdx.x;
  const int lane = tid & 63;
  const int wv   = tid >> 6;
  const int l15  = lane & 15;
  const int lg   = lane >> 4;
  const int win  = ((blockIdx.x & 7) << 8) | (blockIdx.x >> 3);
  const int bb   = win >> 8;
  const int wh   = (win >> 4) & 15;
  const int wwi  = win & 15;

  const unsigned short* ywp = y_win + (size_t)win * 12288;
#pragma unroll
  for (int it = 0; it < 6; ++it) {
    int job = tid + 256 * it;
    int t = job / 24;
    int seg = job - t * 24;
    *(u16x8*)&yb[t * XSTR + seg * 8] = *(const u16x8*)&ywp[(size_t)job * 8];
  }
  __syncthreads();

#pragma unroll
  for (int i = 0; i < 3; ++i) {
    const int na = (3 * wv + i) * 16 + l15;
    const int nb = na + 192;
    f32x4 aacc[4], bacc[4];
    const float ba = b1[na], bbv = b1[nb];
#pragma unroll
    for (int m = 0; m < 4; ++m) {
      aacc[m] = (f32x4){ba, ba, ba, ba};
      bacc[m] = (f32x4){bbv, bbv, bbv, bbv};
    }
#pragma unroll
    for (int ks = 0; ks < 6; ++ks) {
      const int k0 = ks * 32 + lg * 8;
      s16x8 af[4];
#pragma unroll
      for (int m = 0; m < 4; ++m)
        af[m] = *(const s16x8*)&yb[(m * 16 + l15) * XSTR + k0];
      s16x8 wa = *(const s16x8*)&w1b[(size_t)na * 192 + k0];
      s16x8 wb = *(const s16x8*)&w1b[(size_t)nb * 192 + k0];
#pragma unroll
      for (int m = 0; m < 4; ++m) {
        aacc[m] = MFMA(af[m], wa, aacc[m]);
        bacc[m] = MFMA(af[m], wb, bacc[m]);
      }
    }
#pragma unroll
    for (int m = 0; m < 4; ++m)
#pragma unroll
      for (int r = 0; r < 4; ++r) {
        const float g = aacc[m][r] * (1.0f / (1.0f + __expf(-bacc[m][r])));
        wk[(m * 16 + lg * 4 + r) * XSTR + na] = f2b(g);
      }
  }
  __syncthreads();

  int ocol[3];
  f32x4 macc[4][3];
#pragma unroll
  for (int i = 0; i < 3; ++i) {
    ocol[i] = (3 * wv + i) * 16 + l15;
    const float bb2 = b2[ocol[i]];
#pragma unroll
    for (int m = 0; m < 4; ++m) macc[m][i] = (f32x4){bb2, bb2, bb2, bb2};
  }
#pragma unroll
  for (int ks = 0; ks < 6; ++ks) {
    const int k0 = ks * 32 + lg * 8;
    s16x8 gf[4];
#pragma unroll
    for (int m = 0; m < 4; ++m)
      gf[m] = *(const s16x8*)&wk[(m * 16 + l15) * XSTR + k0];
#pragma unroll
    for (int i = 0; i < 3; ++i) {
      s16x8 wf = *(const s16x8*)&w2b[(size_t)ocol[i] * 192 + k0];
#pragma unroll
      for (int m = 0; m < 4; ++m) macc[m][i] = MFMA(gf[m], wf, macc[m][i]);
    }
  }
  __syncthreads();
#pragma unroll
  for (int m = 0; m < 4; ++m)
#pragma unroll
    for (int i = 0; i < 3; ++i)
#pragma unroll
      for (int r = 0; r < 4; ++r)
        wk[(m * 16 + lg * 4 + r) * XSTR + ocol[i]] = f2b(macc[m][i][r]);
  __syncthreads();

  float* obase = out + (size_t)bb * 192 * 16384 + (size_t)(wh * 8) * 128 + wwi * 8;
#pragma unroll
  for (int it = 0; it < 6; ++it) {
    int job = tid + 256 * it;
    int i = job / 192;
    int c = job - i * 192;
    float vals[8];
#pragma unroll
    for (int j = 0; j < 8; ++j) {
      const int t = i * 8 + j;
      vals[j] = b2f(yb[t * XSTR + c]) + b2f(wk[t * XSTR + c]);
    }
    float* dst = obase + (size_t)c * 16384 + i * 128;
    f32x4 o0 = {vals[0], vals[1], vals[2], vals[3]};
    f32x4 o1 = {vals[4], vals[5], vals[6], vals[7]};
    *(f32x4*)dst = o0;
    *(f32x4*)(dst + 4) = o1;
  }
}

// ---------------------------------------------------------------------------
extern "C" void kernel_launch(void* const* d_in, const int* in_sizes, int n_in,
                              void* d_out, int out_size, void* d_ws, size_t ws_size,
                              hipStream_t stream) {
  (void)in_sizes; (void)n_in; (void)out_size; (void)ws_size;
  const float* x          = (const float*)d_in[0];
  const float* qkv_w      = (const float*)d_in[1];
  const float* qkv_b      = (const float*)d_in[2];
  const float* proj_w     = (const float*)d_in[3];
  const float* proj_b     = (const float*)d_in[4];
  const float* mlp1_w     = (const float*)d_in[5];
  const float* mlp1_b     = (const float*)d_in[6];
  const float* mlp2_w     = (const float*)d_in[7];
  const float* mlp2_b     = (const float*)d_in[8];
  const float* bias_table = (const float*)d_in[9];
  const int*   rel_index  = (const int*)d_in[10];
  float* out = (float*)d_out;

  char* ws = (char*)d_ws;
  unsigned short* qkv_wb  = (unsigned short*)ws + WOFF_QKV;
  unsigned short* proj_wb = (unsigned short*)ws + WOFF_PROJ;
  unsigned short* mlp1_wb = (unsigned short*)ws + WOFF_MLP1;
  unsigned short* mlp2_wb = (unsigned short*)ws + WOFF_MLP2;
  unsigned short* biasb   = (unsigned short*)(ws + WOFF_BIASB_BYTES);
  unsigned short* yw      = (unsigned short*)(ws + WOFF_YW_BYTES);

  hipLaunchKernelGGL(prep_kernel, dim3(1024), dim3(256), 0, stream,
                     qkv_w, proj_w, mlp1_w, mlp2_w, bias_table, rel_index,
                     qkv_wb, proj_wb, mlp1_wb, mlp2_wb, biasb);
  hipLaunchKernelGGL(attn_kernel, dim3(1024), dim3(768), 0, stream,
                     x, qkv_wb, qkv_b, proj_wb, proj_b, biasb, yw);
  hipLaunchKernelGGL(mlp_kernel, dim3(2048), dim3(256), 0, stream,
                     yw, mlp1_wb, mlp1_b, mlp2_wb, mlp2_b, out);
}